// Round 1
// 304.748 us; speedup vs baseline: 1.0120x; 1.0120x over previous
//
#include <hip/hip_runtime.h>

constexpr int N_NODES  = 50000;
constexpr int N_EDGES  = 400000;
constexpr int N_GRAPHS = 512;
constexpr int IN_DIM   = 768;
constexpr int HID      = 64;
constexpr float BN_EPS = 1e-5f;
constexpr int CAP      = 64;   // max in-degree ~27 (Poisson 8); 64 is bulletproof

typedef __attribute__((ext_vector_type(8))) short bf16x8;
typedef __attribute__((ext_vector_type(4))) float f32x4;
typedef __attribute__((ext_vector_type(2))) float f32x2;

// HW packed f32->bf16 (RNE), 1 instr per 2 elements (no builtin on gfx950)
__device__ __forceinline__ unsigned int f2bf2(float lo, float hi) {
  unsigned int r;
  asm("v_cvt_pk_bf16_f32 %0, %1, %2" : "=v"(r) : "v"(lo), "v"(hi));
  return r;
}
__device__ __forceinline__ ushort f2bf1(float f) { return (ushort)f2bf2(f, f); }

__device__ __forceinline__ float bf2f(ushort u) {
  return __uint_as_float((unsigned int)u << 16);
}
// unpack 2 bf16 (packed in a uint) -> float2
__device__ __forceinline__ f32x2 unpk(unsigned int u) {
  f32x2 v;
  v.x = __uint_as_float(u << 16);
  v.y = __uint_as_float(u & 0xffff0000u);
  return v;
}

// w1a^T -> WT, {w1b,w2a,w2b}^T -> WT*b (bf16), out = bl bcast, cnt = 0
constexpr int W1A_E = HID * IN_DIM;     // 49152
constexpr int WB_E  = HID * HID;        // 4096
__global__ __launch_bounds__(256) void convert_all(
    const float* __restrict__ w1a, const float* __restrict__ w1b,
    const float* __restrict__ w2a, const float* __restrict__ w2b,
    const float* __restrict__ bl,
    ushort* __restrict__ WT, ushort* __restrict__ WT1b,
    ushort* __restrict__ WT2a, ushort* __restrict__ WT2b,
    float* __restrict__ out, int* __restrict__ cnt) {
  int i = blockIdx.x * 256 + threadIdx.x;
  if (i < W1A_E) {
    int c = i / IN_DIM, k = i - c * IN_DIM;
    WT[i] = f2bf1(w1a[(size_t)k * HID + c]);
    return;
  }
  int j = i - W1A_E;
  if (j < 3 * WB_E) {
    int w = j / WB_E, r = j - w * WB_E;
    int c = r / HID, k = r - c * HID;
    const float* W = (w == 0) ? w1b : (w == 1) ? w2a : w2b;
    ushort* D = (w == 0) ? WT1b : (w == 1) ? WT2a : WT2b;
    D[r] = f2bf1(W[(size_t)k * HID + c]);
    return;
  }
  int o = j - 3 * WB_E;
  if (o < N_GRAPHS * 2) { out[o] = bl[o & 1]; return; }
  int z = o - N_GRAPHS * 2;
  if (z < N_NODES) cnt[z] = 0;
}

constexpr int GB1 = (N_NODES + 127) / 128;   // 391 gemm blocks
constexpr int BB  = (N_EDGES + 255) / 256;   // 1563 build blocks

// Hybrid dispatch: blocks [0,GB1) compute P[n,64] = bf16(X @ w1a) via MFMA
// (128-row tiles); blocks [GB1, GB1+BB) build the dst->src buckets. The
// build's latency-bound atomics hide behind the GEMM's HBM streaming.
// Bucket entries are PRE-MULTIPLIED by HID (element offsets into P).
__global__ __launch_bounds__(256) void gemm_build(const float* __restrict__ X,
                                                  const ushort* __restrict__ WT,
                                                  ushort* __restrict__ P,
                                                  const int* __restrict__ src,
                                                  const int* __restrict__ dst,
                                                  int* __restrict__ cnt,
                                                  int* __restrict__ bucket) {
  const int tid = threadIdx.x;

  if (blockIdx.x >= GB1) {   // ---- bucket build ----
    int e = (blockIdx.x - GB1) * 256 + tid;
    if (e < N_EDGES) {
      int s = src[e];
      int d = dst[e];
      int slot = atomicAdd(&cnt[d], 1);
      if (slot < CAP) bucket[d * CAP + slot] = s << 6;   // s * HID
    }
    return;
  }

  // ---- GEMM: 128-row tile ----
  __shared__ ushort xs[128][64];   // [row][k], 16B chunks XOR-swizzled by row&7
  __shared__ ushort ws[64][64];    // [col][k]
  const int row0 = blockIdx.x * 128;
  const int wave = tid >> 6, lane = tid & 63, quad = lane >> 4, l16 = lane & 15;

  // X staging: 2 threads/row, 32 k-cols each
  const int srow = tid >> 1;
  const int sk   = (tid & 1) * 32;
  int gr = row0 + srow;
  gr = gr < N_NODES ? gr : N_NODES - 1;
  const float* xrow = &X[(size_t)gr * IN_DIM + sk];
  // WT staging: 4 threads/col, TWO 16B chunks each (8 chunks per 64-elem row)
  const int wrow = tid >> 2;
  const int wc0  = (tid & 3) * 2;
  const ushort* wrp = &WT[(size_t)wrow * IN_DIM + wc0 * 8];

  f32x4 acc[2][4] = {};

  float4 xv[8];
#pragma unroll
  for (int i = 0; i < 8; i++) xv[i] = *(const float4*)&xrow[i * 4];
  uint4 wv0 = *(const uint4*)&wrp[0];
  uint4 wv1 = *(const uint4*)&wrp[8];

  for (int kt = 0; kt < IN_DIM; kt += 64) {
    unsigned int xw[16];
#pragma unroll
    for (int i = 0; i < 8; i++) {
      xw[i * 2 + 0] = f2bf2(xv[i].x, xv[i].y);
      xw[i * 2 + 1] = f2bf2(xv[i].z, xv[i].w);
    }
#pragma unroll
    for (int j = 0; j < 4; j++)
      *(uint4*)&xs[srow][(((sk >> 3) + j) ^ (srow & 7)) * 8] = *(const uint4*)&xw[j * 4];
    *(uint4*)&ws[wrow][((wc0 + 0) ^ (wrow & 7)) * 8] = wv0;
    *(uint4*)&ws[wrow][((wc0 + 1) ^ (wrow & 7)) * 8] = wv1;

    // prefetch next tile BEFORE the barrier: loads stay in flight across it
    if (kt + 64 < IN_DIM) {
#pragma unroll
      for (int i = 0; i < 8; i++) xv[i] = *(const float4*)&xrow[kt + 64 + i * 4];
      wv0 = *(const uint4*)&wrp[kt + 64];
      wv1 = *(const uint4*)&wrp[kt + 64 + 8];
    }
    __syncthreads();

    const int ar0 = wave * 32 + l16;
    const int ar1 = ar0 + 16;
#pragma unroll
    for (int ks = 0; ks < 2; ks++) {
      bf16x8 a0 = *(const bf16x8*)&xs[ar0][((ks * 4 + quad) ^ (ar0 & 7)) * 8];
      bf16x8 a1 = *(const bf16x8*)&xs[ar1][((ks * 4 + quad) ^ (ar1 & 7)) * 8];
#pragma unroll
      for (int ct = 0; ct < 4; ct++) {
        const int br = ct * 16 + l16;
        bf16x8 b = *(const bf16x8*)&ws[br][((ks * 4 + quad) ^ (br & 7)) * 8];
        acc[0][ct] = __builtin_amdgcn_mfma_f32_16x16x32_bf16(a0, b, acc[0][ct], 0, 0, 0);
        acc[1][ct] = __builtin_amdgcn_mfma_f32_16x16x32_bf16(a1, b, acc[1][ct], 0, 0, 0);
      }
    }
    __syncthreads();
  }

#pragma unroll
  for (int g2 = 0; g2 < 2; g2++)
#pragma unroll
    for (int ct = 0; ct < 4; ct++)
#pragma unroll
      for (int r = 0; r < 4; r++) {
        int row = row0 + wave * 32 + g2 * 16 + quad * 4 + r;
        if (row < N_NODES)
          P[(size_t)row * HID + ct * 16 + l16] = f2bf1(acc[g2][ct][r]);
      }
}

// Fused GIN layer: gather(Pin)+BN/ReLU staging + MFMA(WT1)+b1+ReLU = xL (regs),
// pool partial: out[batch[n]] += xL[n] . wlh  (LDS gacc -> few global atomics).
// CHAIN: additionally OUT2 = xL_tile @ WT2 (raw) via a 2nd MFMA.
template <int CHAIN>
__global__ __launch_bounds__(256) void fused_mlp(
    const int* __restrict__ cnt, const int* __restrict__ bucket,
    const ushort* __restrict__ Pin,
    const float* __restrict__ bin, const float* __restrict__ g,
    const float* __restrict__ be, const float* __restrict__ rm,
    const float* __restrict__ rv,
    const ushort* __restrict__ WT1, const float* __restrict__ b1,
    const ushort* __restrict__ WT2, ushort* __restrict__ OUT2,
    const int* __restrict__ batch, const float* __restrict__ wlh,
    float* __restrict__ out) {
  __shared__ ushort xs[64][64];             // swizzled A-tile
  __shared__ ushort ws[64][64];             // WT1 [col][k] swizzled
  __shared__ ushort ws2[CHAIN ? 64 : 1][64];// WT2 (CHAIN only)
  __shared__ float sS[64], sT[64];
  __shared__ float gacc[N_GRAPHS * 2];      // per-block graph accumulators
  __shared__ float wl_s[2 * HID];           // this layer's half of wl: [64][2]
  __shared__ int   sbatch[64];              // batch ids of this tile (sorted)
  const int tid  = threadIdx.x;
  const int row0 = blockIdx.x * 64;
  const int srow = tid >> 2;        // node-in-tile (staging)
  const int sub  = tid & 3;         // 16-col group
  const int qc0  = sub * 2;         // 16B-chunk pair
  const int sub16 = sub * 16;

  // ---- early issue: heads of the gather dependency chain ----
  int node = row0 + srow;
  node = node < N_NODES ? node : N_NODES - 1;
  const int c_raw = cnt[node];
  const int* bkt = &bucket[node * CAP];
  const int4 pre = *(const int4*)bkt;     // safe read; values used only if c>=4
  unsigned int sw[8];
  {
    const ushort* sp = &Pin[node * HID + sub16];
    *(uint4*)&sw[0] = *(const uint4*)&sp[0];
    *(uint4*)&sw[4] = *(const uint4*)&sp[8];
  }

  if (tid < 64) {
    int nb = row0 + tid;
    sbatch[tid] = batch[nb < N_NODES ? nb : N_NODES - 1];
    float s = g[tid] * rsqrtf(rv[tid] + BN_EPS);
    sS[tid] = s;
    sT[tid] = (bin[tid] - rm[tid]) * s + be[tid];
  }
  if (tid < 2 * HID) wl_s[tid] = wlh[tid];
  {
    uint4 w0 = *(const uint4*)&WT1[(size_t)srow * HID + qc0 * 8];
    uint4 w1 = *(const uint4*)&WT1[(size_t)srow * HID + qc0 * 8 + 8];
    *(uint4*)&ws[srow][((qc0 + 0) ^ (srow & 7)) * 8] = w0;
    *(uint4*)&ws[srow][((qc0 + 1) ^ (srow & 7)) * 8] = w1;
    if (CHAIN) {
      uint4 v0 = *(const uint4*)&WT2[(size_t)srow * HID + qc0 * 8];
      uint4 v1 = *(const uint4*)&WT2[(size_t)srow * HID + qc0 * 8 + 8];
      *(uint4*)&ws2[srow][((qc0 + 0) ^ (srow & 7)) * 8] = v0;
      *(uint4*)&ws2[srow][((qc0 + 1) ^ (srow & 7)) * 8] = v1;
    }
  }
  __syncthreads();   // sS/sT/sbatch/wl_s ready

  // ---- gather + BN + ReLU -> stage h into xs (4 threads/node) ----
  {
    f32x2 acc2[8];
#pragma unroll
    for (int j = 0; j < 8; j++) acc2[j] = unpk(sw[j]);

    int c = c_raw < CAP ? c_raw : CAP;
    int i = 0;
    if (c >= 4) {
      int4 s4 = pre;
      for (; i + 4 <= c; i += 4) {
        const int4 cur = s4;
        if (i + 8 <= c) s4 = *(const int4*)&bkt[i + 4];   // prefetch next chunk
        unsigned int w0[8], w1[8], w2[8], w3[8];
        const ushort* p0 = &Pin[cur.x + sub16];   // offsets pre-multiplied by HID
        const ushort* p1 = &Pin[cur.y + sub16];
        const ushort* p2 = &Pin[cur.z + sub16];
        const ushort* p3 = &Pin[cur.w + sub16];
        *(uint4*)&w0[0] = *(const uint4*)&p0[0]; *(uint4*)&w0[4] = *(const uint4*)&p0[8];
        *(uint4*)&w1[0] = *(const uint4*)&p1[0]; *(uint4*)&w1[4] = *(const uint4*)&p1[8];
        *(uint4*)&w2[0] = *(const uint4*)&p2[0]; *(uint4*)&w2[4] = *(const uint4*)&p2[8];
        *(uint4*)&w3[0] = *(const uint4*)&p3[0]; *(uint4*)&w3[4] = *(const uint4*)&p3[8];
#pragma unroll
        for (int j = 0; j < 8; j++)
          acc2[j] += (unpk(w0[j]) + unpk(w1[j])) + (unpk(w2[j]) + unpk(w3[j]));
      }
    }
    for (; i < c; i++) {
      const ushort* p0 = &Pin[bkt[i] + sub16];
      unsigned int w0[8];
      *(uint4*)&w0[0] = *(const uint4*)&p0[0]; *(uint4*)&w0[4] = *(const uint4*)&p0[8];
#pragma unroll
      for (int j = 0; j < 8; j++) acc2[j] += unpk(w0[j]);
    }

    unsigned int hw[8];
#pragma unroll
    for (int j = 0; j < 8; j++) {
      const int col = sub16 + j * 2;
      float x0 = fmaxf(fmaf(acc2[j].x, sS[col],     sT[col]),     0.0f);
      float x1 = fmaxf(fmaf(acc2[j].y, sS[col + 1], sT[col + 1]), 0.0f);
      hw[j] = f2bf2(x0, x1);
    }
    *(uint4*)&xs[srow][((qc0 + 0) ^ (srow & 7)) * 8] = *(const uint4*)&hw[0];
    *(uint4*)&xs[srow][((qc0 + 1) ^ (srow & 7)) * 8] = *(const uint4*)&hw[4];
  }
  // zero only the graph range this tile touches (batch is sorted)
  const int g0 = sbatch[0], g1 = sbatch[63];
  for (int z = g0 * 2 + tid; z <= g1 * 2 + 1; z += 256) gacc[z] = 0.0f;
  __syncthreads();

  const int wave = tid >> 6, lane = tid & 63, quad = lane >> 4, l16 = lane & 15;
  const int ar = wave * 16 + l16, axor = ar & 7;

  // ---- GEMM 1: h @ W1 ----
  f32x4 acc1[4] = {};
#pragma unroll
  for (int ks = 0; ks < 2; ks++) {
    bf16x8 a = *(const bf16x8*)&xs[ar][((ks * 4 + quad) ^ axor) * 8];
#pragma unroll
    for (int ct = 0; ct < 4; ct++) {
      const int br = ct * 16 + l16;
      bf16x8 b = *(const bf16x8*)&ws[br][((ks * 4 + quad) ^ (br & 7)) * 8];
      acc1[ct] = __builtin_amdgcn_mfma_f32_16x16x32_bf16(a, b, acc1[ct], 0, 0, 0);
    }
  }

  if (CHAIN) __syncthreads();   // all xs reads done before restage overwrite

  // epilogue: xL = relu(acc1 + b1) in fp32 regs (C layout: col=ct*16+l16, row=quad*4+r)
  float v[4][4];
#pragma unroll
  for (int ct = 0; ct < 4; ct++) {
    const float bo = b1[ct * 16 + l16];
#pragma unroll
    for (int r = 0; r < 4; r++) v[ct][r] = fmaxf(acc1[ct][r] + bo, 0.0f);
  }

  // ---- fused pool partial: p[r] = xL[row] . wlh ----
  {
    float p0[4] = {}, p1[4] = {};
#pragma unroll
    for (int ct = 0; ct < 4; ct++) {
      const int col = ct * 16 + l16;
      const float w0 = wl_s[col * 2 + 0], w1 = wl_s[col * 2 + 1];
#pragma unroll
      for (int r = 0; r < 4; r++) {
        p0[r] = fmaf(v[ct][r], w0, p0[r]);
        p1[r] = fmaf(v[ct][r], w1, p1[r]);
      }
    }
#pragma unroll
    for (int m = 1; m < 16; m <<= 1) {
#pragma unroll
      for (int r = 0; r < 4; r++) {
        p0[r] += __shfl_xor(p0[r], m);
        p1[r] += __shfl_xor(p1[r], m);
      }
    }
    if (l16 == 0) {
#pragma unroll
      for (int r = 0; r < 4; r++) {
        int lrow = wave * 16 + quad * 4 + r;
        if (row0 + lrow < N_NODES) {
          int gi = sbatch[lrow];
          atomicAdd(&gacc[gi * 2 + 0], p0[r]);
          atomicAdd(&gacc[gi * 2 + 1], p1[r]);
        }
      }
    }
  }

  if (CHAIN) {
    // restage bf16(xL) into xs, then GEMM 2: xL @ W2 -> OUT2 (raw projection)
#pragma unroll
    for (int ct = 0; ct < 4; ct++) {
      const int col = ct * 16 + l16;
#pragma unroll
      for (int r = 0; r < 4; r++) {
        int lrow = wave * 16 + quad * 4 + r;
        xs[lrow][(((col >> 3) ^ (lrow & 7)) * 8) + (col & 7)] = f2bf1(v[ct][r]);
      }
    }
    __syncthreads();

    f32x4 accB[4] = {};
#pragma unroll
    for (int ks = 0; ks < 2; ks++) {
      bf16x8 a = *(const bf16x8*)&xs[ar][((ks * 4 + quad) ^ axor) * 8];
#pragma unroll
      for (int ct = 0; ct < 4; ct++) {
        const int br = ct * 16 + l16;
        bf16x8 b = *(const bf16x8*)&ws2[br][((ks * 4 + quad) ^ (br & 7)) * 8];
        accB[ct] = __builtin_amdgcn_mfma_f32_16x16x32_bf16(a, b, accB[ct], 0, 0, 0);
      }
    }
#pragma unroll
    for (int ct = 0; ct < 4; ct++) {
      const int col = ct * 16 + l16;
#pragma unroll
      for (int r = 0; r < 4; r++) {
        int grow = row0 + wave * 16 + quad * 4 + r;
        if (grow < N_NODES) OUT2[(size_t)grow * HID + col] = f2bf1(accB[ct][r]);
      }
    }
  }

  // ---- flush per-block graph partials (tiny range: batch is sorted) ----
  __syncthreads();
  for (int z = g0 * 2 + tid; z <= g1 * 2 + 1; z += 256) {
    float vv = gacc[z];
    if (vv != 0.0f) atomicAdd(&out[z], vv);
  }
}

extern "C" void kernel_launch(void* const* d_in, const int* in_sizes, int n_in,
                              void* d_out, int out_size, void* d_ws, size_t ws_size,
                              hipStream_t stream) {
  const float* x   = (const float*)d_in[0];
  const int*   ei  = (const int*)d_in[1];
  const int*   bat = (const int*)d_in[2];
  const float* w1a = (const float*)d_in[3];
  const float* b1a = (const float*)d_in[4];
  const float* g1  = (const float*)d_in[5];
  const float* be1 = (const float*)d_in[6];
  const float* rm1 = (const float*)d_in[7];
  const float* rv1 = (const float*)d_in[8];
  const float* w1b = (const float*)d_in[9];
  const float* b1b = (const float*)d_in[10];
  const float* w2a = (const float*)d_in[11];
  const float* b2a = (const float*)d_in[12];
  const float* g2  = (const float*)d_in[13];
  const float* be2 = (const float*)d_in[14];
  const float* rm2 = (const float*)d_in[15];
  const float* rv2 = (const float*)d_in[16];
  const float* w2b = (const float*)d_in[17];
  const float* b2b = (const float*)d_in[18];
  const float* wl  = (const float*)d_in[19];
  const float* bl  = (const float*)d_in[20];
  float* out = (float*)d_out;

  const int* src = ei;
  const int* dst = ei + N_EDGES;

  const size_t FB = (size_t)N_NODES * HID;
  ushort* P1   = (ushort*)d_ws;              // 6.4 MB
  ushort* P2   = P1 + FB;                    // 6.4 MB
  ushort* WT   = P2 + FB;                    // 96 KB (w1a^T)
  ushort* WT1b = WT + (size_t)W1A_E;         // 8 KB each
  ushort* WT2a = WT1b + WB_E;
  ushort* WT2b = WT2a + WB_E;
  int* cnt     = (int*)(WT2b + WB_E);        // 200 KB
  int* bucket  = cnt + N_NODES;              // 12.8 MB  (total ~26 MB)

  const int GBF = (N_NODES + 63) / 64;       // 782 (fused layers)
  const int CB  = (W1A_E + 3 * WB_E + N_GRAPHS * 2 + N_NODES + 255) / 256;

  // weights->bf16^T, out=bl, cnt=0
  convert_all<<<CB, 256, 0, stream>>>(w1a, w1b, w2a, w2b, bl,
                                      WT, WT1b, WT2a, WT2b, out, cnt);
  // Hybrid: P1 = x @ w1a (MFMA) + bucket build (overlapped, independent)
  gemm_build<<<GB1 + BB, 256, 0, stream>>>(x, WT, P1, src, dst, cnt, bucket);
  // Layer 1: gather(P1)+BN+ReLU, @w1b+b1b+ReLU = x1 (regs); pool x1.wl[0:64];
  //          chain P2 = x1 @ w2a
  fused_mlp<1><<<GBF, 256, 0, stream>>>(cnt, bucket, P1, b1a, g1, be1, rm1, rv1,
                                        WT1b, b1b, WT2a, P2, bat, wl, out);
  // Layer 2: gather(P2)+BN+ReLU, @w2b+b2b+ReLU = x2 (regs); pool x2.wl[64:128]
  fused_mlp<0><<<GBF, 256, 0, stream>>>(cnt, bucket, P2, b2a, g2, be2, rm2, rv2,
                                        WT2b, b2b, nullptr, nullptr, bat,
                                        wl + 2 * HID, out);
}